// Round 1
// baseline (295.971 us; speedup 1.0000x reference)
//
#include <hip/hip_runtime.h>

#define E_EDGES 32768
#define NN 8192
#define HID 128
#define KS 2

typedef _Float16 half8 __attribute__((ext_vector_type(8)));
typedef float f32x4 __attribute__((ext_vector_type(4)));

// ---------------- CSR build (by dst), done once per call ----------------
__global__ void zero_init_k(int* __restrict__ hist, float* __restrict__ pools, int npool) {
  int t = blockIdx.x * 256 + threadIdx.x;
  if (t < NN) hist[t] = 0;
  if (t < npool) pools[t] = 0.f;
}

__global__ void hist_k(const int* __restrict__ dst, int* __restrict__ hist) {
  int e = blockIdx.x * 256 + threadIdx.x;
  if (e < E_EDGES) atomicAdd(&hist[dst[e]], 1);
}

__global__ void scan_k(const int* __restrict__ hist, int* __restrict__ roff, int* __restrict__ cursor) {
  __shared__ int ps[1024];
  int t = threadIdx.x;
  int loc[8]; int s = 0;
  int base = t * 8;
#pragma unroll
  for (int j = 0; j < 8; ++j) { loc[j] = s; s += hist[base + j]; }
  ps[t] = s;
  __syncthreads();
  for (int off = 1; off < 1024; off <<= 1) {
    int v = 0;
    if (t >= off) v = ps[t - off];
    __syncthreads();
    if (t >= off) ps[t] += v;
    __syncthreads();
  }
  int excl = (t == 0) ? 0 : ps[t - 1];
#pragma unroll
  for (int j = 0; j < 8; ++j) { int v = excl + loc[j]; roff[base + j] = v; cursor[base + j] = v; }
  if (t == 1023) roff[NN] = ps[1023];
}

__global__ void scatter_k(const int* __restrict__ dst, int* __restrict__ cursor, int* __restrict__ eidx) {
  int e = blockIdx.x * 256 + threadIdx.x;
  if (e < E_EDGES) { int p = atomicAdd(&cursor[dst[e]], 1); eidx[p] = e; }
}

// ---------------- W2 -> f16 B-matrix in MFMA-fragment-friendly layout -----
// k = h*CI + i for k < 128*CI (theta rows), then CI rows of b2 (he==1 path),
// zero-pad to Kpad. Layout: out[((k>>3)*CO + n)*8 + (k&7)]  (output-linear idx)
template <int CI, int CO>
__global__ void prep_b_k(const float* __restrict__ W2, const float* __restrict__ b2,
                         _Float16* __restrict__ out) {
  constexpr int Kmain = 128 * CI;
  constexpr int Kpad = (Kmain + CI + 31) & ~31;
  int idx = blockIdx.x * 256 + threadIdx.x;
  if (idx >= Kpad * CO) return;
  int j = idx & 7;
  int n = (idx >> 3) & (CO - 1);
  int kg = idx >> (3 + (CO == 64 ? 6 : 5));
  int k = kg * 8 + j;
  float v = 0.f;
  if (k < Kmain) {
    int h = k / CI, i = k & (CI - 1);
    v = W2[(h * CI + i) * CO + n];
  } else if (k < Kmain + CI) {
    int tt = k - Kmain;
    v = b2[tt * CO + n];
  }
  out[idx] = (_Float16)v;
}

// ---------------- main fused kernel: edge MLP1 + Z@W2r GEMM (split-K) -----
// msg[e,o] partial (for this k-range) = sum_k Z[e,k]*B[k,o],
//   Z[e, h*CI+i] = x[src_e, i] * relu(eattr[e]@W1 + b1)[h]   (tail rows: he=1)
template <int CI, int CO>
__launch_bounds__(256, 2)
__global__ void msg_mfma_k(const float* __restrict__ xcur, const int* __restrict__ src,
                           const float* __restrict__ eattr, const float* __restrict__ W1,
                           const float* __restrict__ b1, const _Float16* __restrict__ Bsw,
                           float* __restrict__ msgbuf) {
  constexpr int ME = 128;                      // edges per block
  constexpr int L2CI = (CI == 64) ? 6 : ((CI == 32) ? 5 : 4);
  constexpr int Kmain = 128 * CI;
  constexpr int Kpad = (Kmain + CI + 31) & ~31;
  constexpr int NK = Kpad / 32;
  constexpr int CSPLIT = 2 * CI;               // chunks covering h in [0,64)
  constexpr int XSTR = CI + 8;                 // pad to kill 16-way bank conflicts
  constexpr int SBH = 32 * CO;                 // halfs per 32-k slab
  constexpr int FC = CO / 16;
  constexpr int NV4 = SBH / 8;                 // float4 per slab (<=256)

  __shared__ _Float16 he_s[64 * ME];           // [h-local][e]
  __shared__ _Float16 xs_s[ME * XSTR];         // [e][i]
  __shared__ _Float16 w2_s[2 * SBH];           // double-buffered B slab
  __shared__ float ea_s[ME * 5];
  __shared__ float W1s[5 * 64];
  __shared__ float b1s[64];
  __shared__ int src_s[ME];

  int t = threadIdx.x;
  int e0 = blockIdx.x * ME;
  int y = blockIdx.y;
  int hbeg = y * 64;

  // phase 1: stage eattr rows, W1/b1 slices, src indices
  for (int j = t; j < ME * 5; j += 256) ea_s[j] = eattr[e0 * 5 + j];
  for (int j = t; j < 5 * 64; j += 256) W1s[j] = W1[(j >> 6) * HID + hbeg + (j & 63)];
  if (t < 64) b1s[t] = b1[hbeg + t];
  if (t < ME) src_s[t] = src[e0 + t];
  __syncthreads();

  // phase 2: edge MLP1 (only this block's h-range), x gather, first B slab
  for (int j = t; j < 64 * ME; j += 256) {
    int hl = j >> 7, e = j & 127;
    float v = b1s[hl];
#pragma unroll
    for (int d = 0; d < 5; ++d) v += ea_s[e * 5 + d] * W1s[d * 64 + hl];
    he_s[hl * ME + e] = (_Float16)fmaxf(v, 0.f);
  }
  for (int j = t; j < ME * CI; j += 256) {
    int e = j >> L2CI, i = j & (CI - 1);
    xs_s[e * XSTR + i] = (_Float16)xcur[src_s[e] * CI + i];
  }
  int cbeg = y ? CSPLIT : 0;
  int cend = y ? NK : CSPLIT;
  if (t < NV4) ((float4*)w2_s)[t] = ((const float4*)(Bsw + (size_t)cbeg * SBH))[t];
  __syncthreads();

  int lane = t & 63;
  int w = t >> 6;
  int quad = lane >> 4, l15 = lane & 15;
  int eA0 = w * 32 + l15;

  f32x4 acc[2][FC];
#pragma unroll
  for (int fr = 0; fr < 2; ++fr)
#pragma unroll
    for (int fc = 0; fc < FC; ++fc)
#pragma unroll
      for (int r = 0; r < 4; ++r) acc[fr][fc][r] = 0.f;

  for (int c = cbeg; c < cend; ++c) {
    int p = (c - cbeg) & 1;
    float4 pf;
    bool more = (c + 1 < cend);
    if (more && t < NV4) pf = ((const float4*)(Bsw + (size_t)(c + 1) * SBH))[t];

    int kq = c * 32 + quad * 8;
    int i = kq & (CI - 1);
    half8 a[2];
    if (c * 32 < Kmain) {
      int hr = (kq >> L2CI) - hbeg;
#pragma unroll
      for (int fr = 0; fr < 2; ++fr) {
        int e = eA0 + 16 * fr;
        _Float16 hv = he_s[hr * ME + e];
        half8 xv = *(const half8*)&xs_s[e * XSTR + i];
        a[fr] = xv * hv;                       // v_pk_mul_f16 x4
      }
    } else {                                   // b2 tail rows: he == 1
#pragma unroll
      for (int fr = 0; fr < 2; ++fr) {
        int e = eA0 + 16 * fr;
        a[fr] = *(const half8*)&xs_s[e * XSTR + i];
      }
    }
    const _Float16* wb = w2_s + p * SBH + quad * (CO * 8);
#pragma unroll
    for (int fc = 0; fc < FC; ++fc) {
      half8 b = *(const half8*)&wb[(fc * 16 + l15) * 8];
      acc[0][fc] = __builtin_amdgcn_mfma_f32_16x16x32_f16(a[0], b, acc[0][fc], 0, 0, 0);
      acc[1][fc] = __builtin_amdgcn_mfma_f32_16x16x32_f16(a[1], b, acc[1][fc], 0, 0, 0);
    }
    __syncthreads();
    if (more && t < NV4) ((float4*)(w2_s + (1 - p) * SBH))[t] = pf;
    __syncthreads();
  }

  // epilogue: plain (non-atomic) partial writes; C/D: row=(lane>>4)*4+r, col=lane&15
  float* mb = msgbuf + ((size_t)y * E_EDGES + e0) * CO;
#pragma unroll
  for (int fr = 0; fr < 2; ++fr)
#pragma unroll
    for (int fc = 0; fc < FC; ++fc)
#pragma unroll
      for (int r = 0; r < 4; ++r) {
        int el = w * 32 + fr * 16 + quad * 4 + r;
        int o = fc * 16 + l15;
        mb[el * CO + o] = acc[fr][fc][r];
      }
}

// ---------------- scatter-sum via CSR gather + x@root + bias + ELU --------
template <int CI, int CO>
__global__ void gather_elu_k(const float* __restrict__ xcur, const float* __restrict__ root,
                             const float* __restrict__ bias, const float* __restrict__ msgbuf,
                             const int* __restrict__ roff, const int* __restrict__ eidx,
                             float* __restrict__ xnext) {
  constexpr int NB = 256 / CO;
  __shared__ float xs[NB * CI];
  int t = threadIdx.x;
  int n0 = blockIdx.x * NB;
  for (int j = t; j < NB * CI; j += 256) xs[j] = xcur[n0 * CI + j];
  __syncthreads();
  int nl = t / CO, o = t & (CO - 1);
  int n = n0 + nl;
  float a = bias[o];
#pragma unroll
  for (int i = 0; i < CI; ++i) a += xs[nl * CI + i] * root[i * CO + o];
  int j1 = roff[n + 1];
  for (int j = roff[n]; j < j1; ++j) {
    int e = eidx[j];
    a += msgbuf[(size_t)e * CO + o] + msgbuf[((size_t)E_EDGES + e) * CO + o];
  }
  xnext[n * CO + o] = a > 0.f ? a : expm1f(a);
}

// ---------------- pooling + MLP head --------------------------------------
__global__ void pool_sub_k(const float* __restrict__ x3, const int* __restrict__ n2s,
                           float* __restrict__ ssum, float* __restrict__ scnt) {
  int idx = blockIdx.x * 256 + threadIdx.x;  // over NN*64
  int n = idx >> 6, o = idx & 63;
  int s = n2s[n];
  atomicAdd(&ssum[(s << 6) + o], x3[idx]);
  if (o == 0) atomicAdd(&scnt[s], 1.f);
}

__global__ void pool_graph_k(const float* __restrict__ ssum, const float* __restrict__ scnt,
                             const int* __restrict__ s2g, float* __restrict__ gsum,
                             float* __restrict__ gcnt) {
  int idx = blockIdx.x * 256 + threadIdx.x;  // over 512*64
  int s = idx >> 6, o = idx & 63;
  int g = s2g[s];
  float v = ssum[idx] / fmaxf(scnt[s], 1.f);
  atomicAdd(&gsum[(g << 6) + o], v);
  if (o == 0) atomicAdd(&gcnt[g], 1.f);
}

__global__ void head_k(const float* __restrict__ gsum, const float* __restrict__ gcnt,
                       const float* __restrict__ w1, const float* __restrict__ b1,
                       const float* __restrict__ w2, const float* __restrict__ b2,
                       const float* __restrict__ w3, const float* __restrict__ b3,
                       float* __restrict__ out) {
  int g = blockIdx.x;
  int t = threadIdx.x;  // 64 threads
  __shared__ float m[64], s1[32], s2[16];
  float c = fmaxf(gcnt[g], 1.f);
  m[t] = gsum[g * 64 + t] / c;
  __syncthreads();
  if (t < 32) {
    float a = b1[t];
    for (int i = 0; i < 64; ++i) a += m[i] * w1[i * 32 + t];
    s1[t] = a > 0.f ? a : expm1f(a);
  }
  __syncthreads();
  if (t < 16) {
    float a = b2[t];
    for (int i = 0; i < 32; ++i) a += s1[i] * w2[i * 16 + t];
    s2[t] = a > 0.f ? a : expm1f(a);
  }
  __syncthreads();
  if (t == 0) {
    float a = b3[0];
    for (int i = 0; i < 16; ++i) a += s2[i] * w3[i];
    out[g] = a;
  }
}

extern "C" void kernel_launch(void* const* d_in, const int* in_sizes, int n_in,
                              void* d_out, int out_size, void* d_ws, size_t ws_size,
                              hipStream_t stream) {
  (void)in_sizes; (void)n_in; (void)out_size; (void)ws_size;
  const float* x0 = (const float*)d_in[0];
  const int* ei = (const int*)d_in[1];
  const float* ea = (const float*)d_in[2];
  const int* n2s = (const int*)d_in[3];
  const int* s2g = (const int*)d_in[4];
  const float* W1_[3] = {(const float*)d_in[5], (const float*)d_in[11], (const float*)d_in[17]};
  const float* b1_[3] = {(const float*)d_in[6], (const float*)d_in[12], (const float*)d_in[18]};
  const float* W2_[3] = {(const float*)d_in[7], (const float*)d_in[13], (const float*)d_in[19]};
  const float* b2_[3] = {(const float*)d_in[8], (const float*)d_in[14], (const float*)d_in[20]};
  const float* rt_[3] = {(const float*)d_in[9], (const float*)d_in[15], (const float*)d_in[21]};
  const float* bs_[3] = {(const float*)d_in[10], (const float*)d_in[16], (const float*)d_in[22]};
  const float* fc1w = (const float*)d_in[23]; const float* fc1b = (const float*)d_in[24];
  const float* fc2w = (const float*)d_in[25]; const float* fc2b = (const float*)d_in[26];
  const float* fc3w = (const float*)d_in[27]; const float* fc3b = (const float*)d_in[28];
  float* out = (float*)d_out;

  const int* srcp = ei;
  const int* dstp = ei + E_EDGES;

  char* wsb = (char*)d_ws;
  size_t off = 0;
  auto alloc = [&](size_t bytes) {
    void* p = wsb + off;
    off += (bytes + 255) & ~(size_t)255;
    return p;
  };
  _Float16* Bsw0 = (_Float16*)alloc((size_t)2080 * 32 * 2);
  _Float16* Bsw1 = (_Float16*)alloc((size_t)4128 * 64 * 2);
  _Float16* Bsw2 = (_Float16*)alloc((size_t)8256 * 64 * 2);
  float* msgbuf = (float*)alloc((size_t)KS * E_EDGES * 64 * 4);
  float* x1 = (float*)alloc((size_t)NN * 32 * 4);
  float* x2 = (float*)alloc((size_t)NN * 64 * 4);
  float* x3 = (float*)alloc((size_t)NN * 64 * 4);
  int* hist = (int*)alloc((size_t)NN * 4);
  int* roff = (int*)alloc((size_t)(NN + 1) * 4);
  int* cursor = (int*)alloc((size_t)NN * 4);
  int* eidx = (int*)alloc((size_t)E_EDGES * 4);
  const int npool = 512 * 64 + 512 + 32 * 64 + 32;
  float* pools = (float*)alloc((size_t)npool * 4);
  float* ssum = pools;
  float* scnt = pools + 512 * 64;
  float* gsum = scnt + 512;
  float* gcnt = gsum + 32 * 64;

  zero_init_k<<<(npool + 255) / 256, 256, 0, stream>>>(hist, pools, npool);
  hist_k<<<E_EDGES / 256, 256, 0, stream>>>(dstp, hist);
  scan_k<<<1, 1024, 0, stream>>>(hist, roff, cursor);
  scatter_k<<<E_EDGES / 256, 256, 0, stream>>>(dstp, cursor, eidx);
  prep_b_k<16, 32><<<(2080 * 32 + 255) / 256, 256, 0, stream>>>(W2_[0], b2_[0], Bsw0);
  prep_b_k<32, 64><<<(4128 * 64 + 255) / 256, 256, 0, stream>>>(W2_[1], b2_[1], Bsw1);
  prep_b_k<64, 64><<<(8256 * 64 + 255) / 256, 256, 0, stream>>>(W2_[2], b2_[2], Bsw2);

  dim3 mg(E_EDGES / 128, KS);
  msg_mfma_k<16, 32><<<mg, 256, 0, stream>>>(x0, srcp, ea, W1_[0], b1_[0], Bsw0, msgbuf);
  gather_elu_k<16, 32><<<NN / 8, 256, 0, stream>>>(x0, rt_[0], bs_[0], msgbuf, roff, eidx, x1);
  msg_mfma_k<32, 64><<<mg, 256, 0, stream>>>(x1, srcp, ea, W1_[1], b1_[1], Bsw1, msgbuf);
  gather_elu_k<32, 64><<<NN / 4, 256, 0, stream>>>(x1, rt_[1], bs_[1], msgbuf, roff, eidx, x2);
  msg_mfma_k<64, 64><<<mg, 256, 0, stream>>>(x2, srcp, ea, W1_[2], b1_[2], Bsw2, msgbuf);
  gather_elu_k<64, 64><<<NN / 4, 256, 0, stream>>>(x2, rt_[2], bs_[2], msgbuf, roff, eidx, x3);

  pool_sub_k<<<NN * 64 / 256, 256, 0, stream>>>(x3, n2s, ssum, scnt);
  pool_graph_k<<<512 * 64 / 256, 256, 0, stream>>>(ssum, scnt, s2g, gsum, gcnt);
  head_k<<<32, 64, 0, stream>>>(gsum, gcnt, fc1w, fc1b, fc2w, fc2b, fc3w, fc3b, out);
}

// Round 2
// 269.556 us; speedup vs baseline: 1.0980x; 1.0980x over previous
//
#include <hip/hip_runtime.h>

#define E_EDGES 32768
#define NN 8192
#define HID 128
#define KS 4

typedef _Float16 half8 __attribute__((ext_vector_type(8)));
typedef _Float16 half4 __attribute__((ext_vector_type(4)));
typedef float f32x4 __attribute__((ext_vector_type(4)));

// ---------------- CSR build (by dst), done once per call ----------------
__global__ void zero_init_k(int* __restrict__ hist, float* __restrict__ pools, int npool) {
  int t = blockIdx.x * 256 + threadIdx.x;
  if (t < NN) hist[t] = 0;
  if (t < npool) pools[t] = 0.f;
}

__global__ void hist_k(const int* __restrict__ dst, int* __restrict__ hist) {
  int e = blockIdx.x * 256 + threadIdx.x;
  if (e < E_EDGES) atomicAdd(&hist[dst[e]], 1);
}

__global__ void scan_k(const int* __restrict__ hist, int* __restrict__ roff, int* __restrict__ cursor) {
  __shared__ int ps[1024];
  int t = threadIdx.x;
  int loc[8]; int s = 0;
  int base = t * 8;
#pragma unroll
  for (int j = 0; j < 8; ++j) { loc[j] = s; s += hist[base + j]; }
  ps[t] = s;
  __syncthreads();
  for (int off = 1; off < 1024; off <<= 1) {
    int v = 0;
    if (t >= off) v = ps[t - off];
    __syncthreads();
    if (t >= off) ps[t] += v;
    __syncthreads();
  }
  int excl = (t == 0) ? 0 : ps[t - 1];
#pragma unroll
  for (int j = 0; j < 8; ++j) { int v = excl + loc[j]; roff[base + j] = v; cursor[base + j] = v; }
  if (t == 1023) roff[NN] = ps[1023];
}

__global__ void scatter_k(const int* __restrict__ dst, int* __restrict__ cursor, int* __restrict__ eidx) {
  int e = blockIdx.x * 256 + threadIdx.x;
  if (e < E_EDGES) { int p = atomicAdd(&cursor[dst[e]], 1); eidx[p] = e; }
}

// ---------------- W2 -> f16 B-matrix in MFMA-fragment-linear layout -------
// Linear padded k-space: k<128*CI theta rows (k=h*CI+i), next CI rows = b2
// (he==1 path), zero to Kpad. Layout: out[((k>>3)*CO + n)*8 + (k&7)] so a
// b-fragment (8 k x 16 n for one lane) is one contiguous 16B chunk.
template <int CI, int CO>
__global__ void prep_b_k(const float* __restrict__ W2, const float* __restrict__ b2,
                         _Float16* __restrict__ out) {
  constexpr int Kmain = 128 * CI;
  constexpr int SPLITK = 32 * CI;
  constexpr int TAILK = ((SPLITK + CI + 127) / 128) * 128;
  constexpr int Kpad = 3 * SPLITK + TAILK;
  int idx = blockIdx.x * 256 + threadIdx.x;
  if (idx >= Kpad * CO) return;
  int j = idx & 7;
  int n = (idx >> 3) & (CO - 1);
  int kg = idx >> (3 + (CO == 64 ? 6 : 5));
  int k = kg * 8 + j;
  float v = 0.f;
  if (k < Kmain) {
    int h = k / CI, i = k & (CI - 1);
    v = W2[(h * CI + i) * CO + n];
  } else if (k < Kmain + CI) {
    int tt = k - Kmain;
    v = b2[tt * CO + n];
  }
  out[idx] = (_Float16)v;
}

// ---------------- main fused kernel: edge MLP1 + Z@W2r GEMM (split-K=4) ---
// Barrier-free K-loop: he/xs staged once; B-fragments streamed from global
// (L2-resident) via depth-4 rotating register prefetch. No __syncthreads in
// the hot loop -> compiler software-pipelines, vmcnt never drains to 0.
template <int CI, int CO>
__launch_bounds__(256, 2)
__global__ void msg_mfma_k(const float* __restrict__ xcur, const int* __restrict__ src,
                           const float* __restrict__ eattr, const float* __restrict__ W1,
                           const float* __restrict__ b1, const _Float16* __restrict__ Bsw,
                           float* __restrict__ msgbuf) {
  constexpr int ME = 256;                      // edges per block
  constexpr int L2CI = (CI == 64) ? 6 : ((CI == 32) ? 5 : 4);
  constexpr int Kmain = 128 * CI;
  constexpr int SPLITK = 32 * CI;              // k per split (splits 0..2)
  constexpr int TAILK = ((SPLITK + CI + 127) / 128) * 128;
  constexpr int XSTR = CI + 8;                 // LDS pad: 2-way-max bank aliasing
  constexpr int FC = CO / 16;
  constexpr int C4 = CI / 4;
  constexpr int L2C4 = L2CI - 2;

  __shared__ _Float16 he_s[32 * ME];           // [h-local(32)][e]
  __shared__ _Float16 xs_s[ME * XSTR];         // [e][i]
  __shared__ float ea_s[ME * 5];
  __shared__ float W1s[5 * 32];
  __shared__ float b1s[32];
  __shared__ int src_s[ME];

  int t = threadIdx.x;
  int e0 = blockIdx.x * ME;
  int y = blockIdx.y;                          // split: h in [32y, 32y+32)
  int hbeg = y * 32;

  // phase 1: stage eattr rows, W1/b1 slice, src indices
  for (int j = t; j < ME * 5; j += 256) ea_s[j] = eattr[e0 * 5 + j];
  if (t < 5 * 32) W1s[t] = W1[(t >> 5) * HID + hbeg + (t & 31)];
  if (t < 32) b1s[t] = b1[hbeg + t];
  src_s[t] = src[e0 + t];
  __syncthreads();

  // phase 2: edge MLP1 (this split's 32 h only) + x gather (f32x4 -> f16)
  for (int j = t; j < 32 * ME; j += 256) {
    int hl = j / ME, e = j & (ME - 1);
    float v = b1s[hl];
#pragma unroll
    for (int d = 0; d < 5; ++d) v += ea_s[e * 5 + d] * W1s[d * 32 + hl];
    he_s[hl * ME + e] = (_Float16)fmaxf(v, 0.f);
  }
  for (int j = t; j < ME * C4; j += 256) {
    int e = j >> L2C4, i4 = j & (C4 - 1);
    float4 v = ((const float4*)xcur)[src_s[e] * C4 + i4];
    half4 hq = {(_Float16)v.x, (_Float16)v.y, (_Float16)v.z, (_Float16)v.w};
    *(half4*)&xs_s[e * XSTR + i4 * 4] = hq;
  }
  __syncthreads();                             // last barrier before K-loop

  int lane = t & 63;
  int w = t >> 6;
  int quad = lane >> 4, l15 = lane & 15;

  int cbeg = y * (SPLITK / 32);
  int cend = cbeg + ((y < 3) ? (SPLITK / 32) : (TAILK / 32));
  int nrounds = (cend - cbeg) >> 2;

  const half8* bsw8 = (const half8*)Bsw;
  int ib = quad * CO + l15;                    // per-lane b-frag offset

  f32x4 acc[4][FC];
#pragma unroll
  for (int fr = 0; fr < 4; ++fr)
#pragma unroll
    for (int fc = 0; fc < FC; ++fc)
#pragma unroll
      for (int r = 0; r < 4; ++r) acc[fr][fc][r] = 0.f;

  // preload B fragments for first 4 chunks
  half8 breg[4][FC];
#pragma unroll
  for (int j = 0; j < 4; ++j)
#pragma unroll
    for (int fc = 0; fc < FC; ++fc)
      breg[j][fc] = bsw8[(cbeg + j) * 4 * CO + ib + fc * 16];

  for (int r = 0; r < nrounds; ++r) {
#pragma unroll
    for (int j = 0; j < 4; ++j) {
      int c = cbeg + r * 4 + j;
      int kq = c * 32 + quad * 8;
      int i = kq & (CI - 1);
      int hr = (kq >> L2CI) - hbeg;
      half8 a[4];
#pragma unroll
      for (int fr = 0; fr < 4; ++fr) {
        int e = w * 64 + fr * 16 + l15;
        half8 xv = *(const half8*)&xs_s[e * XSTR + i];
        _Float16 hv = (_Float16)1.f;
        if (kq < Kmain) hv = he_s[hr * ME + e];
        a[fr] = xv * hv;
      }
#pragma unroll
      for (int fc = 0; fc < FC; ++fc) {
#pragma unroll
        for (int fr = 0; fr < 4; ++fr)
          acc[fr][fc] = __builtin_amdgcn_mfma_f32_16x16x32_f16(a[fr], breg[j][fc], acc[fr][fc], 0, 0, 0);
      }
      int cn = c + 4;
      if (cn >= cend) cn = cend - 1;           // clamped: branch-free prefetch
#pragma unroll
      for (int fc = 0; fc < FC; ++fc)
        breg[j][fc] = bsw8[cn * 4 * CO + ib + fc * 16];
    }
  }

  // epilogue: plain partial writes; C/D: row(e)=quad*4+r, col(o)=l15
  float* mb = msgbuf + ((size_t)y * E_EDGES + e0) * CO;
#pragma unroll
  for (int fr = 0; fr < 4; ++fr)
#pragma unroll
    for (int fc = 0; fc < FC; ++fc)
#pragma unroll
      for (int r = 0; r < 4; ++r) {
        int el = w * 64 + fr * 16 + quad * 4 + r;
        int o = fc * 16 + l15;
        mb[el * CO + o] = acc[fr][fc][r];
      }
}

// ---------------- scatter-sum via CSR gather + x@root + bias + ELU --------
template <int CI, int CO>
__global__ void gather_elu_k(const float* __restrict__ xcur, const float* __restrict__ root,
                             const float* __restrict__ bias, const float* __restrict__ msgbuf,
                             const int* __restrict__ roff, const int* __restrict__ eidx,
                             float* __restrict__ xnext) {
  constexpr int NB = 256 / CO;
  __shared__ float xs[NB * CI];
  int t = threadIdx.x;
  int n0 = blockIdx.x * NB;
  for (int j = t; j < NB * CI; j += 256) xs[j] = xcur[n0 * CI + j];
  __syncthreads();
  int nl = t / CO, o = t & (CO - 1);
  int n = n0 + nl;
  float a = bias[o];
#pragma unroll
  for (int i = 0; i < CI; ++i) a += xs[nl * CI + i] * root[i * CO + o];
  int j1 = roff[n + 1];
  for (int j = roff[n]; j < j1; ++j) {
    int e = eidx[j];
    float m = 0.f;
#pragma unroll
    for (int s = 0; s < KS; ++s) m += msgbuf[((size_t)s * E_EDGES + e) * CO + o];
    a += m;
  }
  xnext[n * CO + o] = a > 0.f ? a : expm1f(a);
}

// ---------------- pooling + MLP head --------------------------------------
__global__ void pool_sub_k(const float* __restrict__ x3, const int* __restrict__ n2s,
                           float* __restrict__ ssum, float* __restrict__ scnt) {
  int idx = blockIdx.x * 256 + threadIdx.x;  // over NN*64
  int n = idx >> 6, o = idx & 63;
  int s = n2s[n];
  atomicAdd(&ssum[(s << 6) + o], x3[idx]);
  if (o == 0) atomicAdd(&scnt[s], 1.f);
}

__global__ void pool_graph_k(const float* __restrict__ ssum, const float* __restrict__ scnt,
                             const int* __restrict__ s2g, float* __restrict__ gsum,
                             float* __restrict__ gcnt) {
  int idx = blockIdx.x * 256 + threadIdx.x;  // over 512*64
  int s = idx >> 6, o = idx & 63;
  int g = s2g[s];
  float v = ssum[idx] / fmaxf(scnt[s], 1.f);
  atomicAdd(&gsum[(g << 6) + o], v);
  if (o == 0) atomicAdd(&gcnt[g], 1.f);
}

__global__ void head_k(const float* __restrict__ gsum, const float* __restrict__ gcnt,
                       const float* __restrict__ w1, const float* __restrict__ b1,
                       const float* __restrict__ w2, const float* __restrict__ b2,
                       const float* __restrict__ w3, const float* __restrict__ b3,
                       float* __restrict__ out) {
  int g = blockIdx.x;
  int t = threadIdx.x;  // 64 threads
  __shared__ float m[64], s1[32], s2[16];
  float c = fmaxf(gcnt[g], 1.f);
  m[t] = gsum[g * 64 + t] / c;
  __syncthreads();
  if (t < 32) {
    float a = b1[t];
    for (int i = 0; i < 64; ++i) a += m[i] * w1[i * 32 + t];
    s1[t] = a > 0.f ? a : expm1f(a);
  }
  __syncthreads();
  if (t < 16) {
    float a = b2[t];
    for (int i = 0; i < 32; ++i) a += s1[i] * w2[i * 16 + t];
    s2[t] = a > 0.f ? a : expm1f(a);
  }
  __syncthreads();
  if (t == 0) {
    float a = b3[0];
    for (int i = 0; i < 16; ++i) a += s2[i] * w3[i];
    out[g] = a;
  }
}

extern "C" void kernel_launch(void* const* d_in, const int* in_sizes, int n_in,
                              void* d_out, int out_size, void* d_ws, size_t ws_size,
                              hipStream_t stream) {
  (void)in_sizes; (void)n_in; (void)out_size; (void)ws_size;
  const float* x0 = (const float*)d_in[0];
  const int* ei = (const int*)d_in[1];
  const float* ea = (const float*)d_in[2];
  const int* n2s = (const int*)d_in[3];
  const int* s2g = (const int*)d_in[4];
  const float* W1_[3] = {(const float*)d_in[5], (const float*)d_in[11], (const float*)d_in[17]};
  const float* b1_[3] = {(const float*)d_in[6], (const float*)d_in[12], (const float*)d_in[18]};
  const float* W2_[3] = {(const float*)d_in[7], (const float*)d_in[13], (const float*)d_in[19]};
  const float* b2_[3] = {(const float*)d_in[8], (const float*)d_in[14], (const float*)d_in[20]};
  const float* rt_[3] = {(const float*)d_in[9], (const float*)d_in[15], (const float*)d_in[21]};
  const float* bs_[3] = {(const float*)d_in[10], (const float*)d_in[16], (const float*)d_in[22]};
  const float* fc1w = (const float*)d_in[23]; const float* fc1b = (const float*)d_in[24];
  const float* fc2w = (const float*)d_in[25]; const float* fc2b = (const float*)d_in[26];
  const float* fc3w = (const float*)d_in[27]; const float* fc3b = (const float*)d_in[28];
  float* out = (float*)d_out;

  const int* srcp = ei;
  const int* dstp = ei + E_EDGES;

  char* wsb = (char*)d_ws;
  size_t off = 0;
  auto alloc = [&](size_t bytes) {
    void* p = wsb + off;
    off += (bytes + 255) & ~(size_t)255;
    return p;
  };
  // Kpad: L0(CI=16): 2176, L1(CI=32): 4224, L2(CI=64): 8320
  _Float16* Bsw0 = (_Float16*)alloc((size_t)2176 * 32 * 2);
  _Float16* Bsw1 = (_Float16*)alloc((size_t)4224 * 64 * 2);
  _Float16* Bsw2 = (_Float16*)alloc((size_t)8320 * 64 * 2);
  float* msgbuf = (float*)alloc((size_t)KS * E_EDGES * 64 * 4);
  float* x1 = (float*)alloc((size_t)NN * 32 * 4);
  float* x2 = (float*)alloc((size_t)NN * 64 * 4);
  float* x3 = (float*)alloc((size_t)NN * 64 * 4);
  int* hist = (int*)alloc((size_t)NN * 4);
  int* roff = (int*)alloc((size_t)(NN + 1) * 4);
  int* cursor = (int*)alloc((size_t)NN * 4);
  int* eidx = (int*)alloc((size_t)E_EDGES * 4);
  const int npool = 512 * 64 + 512 + 32 * 64 + 32;
  float* pools = (float*)alloc((size_t)npool * 4);
  float* ssum = pools;
  float* scnt = pools + 512 * 64;
  float* gsum = scnt + 512;
  float* gcnt = gsum + 32 * 64;

  zero_init_k<<<(npool + 255) / 256, 256, 0, stream>>>(hist, pools, npool);
  hist_k<<<E_EDGES / 256, 256, 0, stream>>>(dstp, hist);
  scan_k<<<1, 1024, 0, stream>>>(hist, roff, cursor);
  scatter_k<<<E_EDGES / 256, 256, 0, stream>>>(dstp, cursor, eidx);
  prep_b_k<16, 32><<<(2176 * 32 + 255) / 256, 256, 0, stream>>>(W2_[0], b2_[0], Bsw0);
  prep_b_k<32, 64><<<(4224 * 64 + 255) / 256, 256, 0, stream>>>(W2_[1], b2_[1], Bsw1);
  prep_b_k<64, 64><<<(8320 * 64 + 255) / 256, 256, 0, stream>>>(W2_[2], b2_[2], Bsw2);

  dim3 mg(E_EDGES / 256, KS);
  msg_mfma_k<16, 32><<<mg, 256, 0, stream>>>(x0, srcp, ea, W1_[0], b1_[0], Bsw0, msgbuf);
  gather_elu_k<16, 32><<<NN / 8, 256, 0, stream>>>(x0, rt_[0], bs_[0], msgbuf, roff, eidx, x1);
  msg_mfma_k<32, 64><<<mg, 256, 0, stream>>>(x1, srcp, ea, W1_[1], b1_[1], Bsw1, msgbuf);
  gather_elu_k<32, 64><<<NN / 4, 256, 0, stream>>>(x1, rt_[1], bs_[1], msgbuf, roff, eidx, x2);
  msg_mfma_k<64, 64><<<mg, 256, 0, stream>>>(x2, srcp, ea, W1_[2], b1_[2], Bsw2, msgbuf);
  gather_elu_k<64, 64><<<NN / 4, 256, 0, stream>>>(x2, rt_[2], bs_[2], msgbuf, roff, eidx, x3);

  pool_sub_k<<<NN * 64 / 256, 256, 0, stream>>>(x3, n2s, ssum, scnt);
  pool_graph_k<<<512 * 64 / 256, 256, 0, stream>>>(ssum, scnt, s2g, gsum, gcnt);
  head_k<<<32, 64, 0, stream>>>(gsum, gcnt, fc1w, fc1b, fc2w, fc2b, fc3w, fc3b, out);
}